// Round 10
// baseline (31.556 us; speedup 1.0000x reference)
//
#include <hip/hip_runtime.h>
#include <math.h>

constexpr int NT   = 256;   // threads per block (4 waves = 2 batches x 2 waves)
constexpr int DIMV = 256;   // volume D=H=W
constexpr int RS   = 8;     // staged region side (voxels)
constexpr int QROW = 9;     // packed row stride (float4 quad slots)
constexpr int QSLICE = RS * QROW;   // 72 slots per z-slice

__device__ __forceinline__ float rflf(float x) {
    return __uint_as_float(__builtin_amdgcn_readfirstlane(__float_as_uint(x)));
}
__device__ __forceinline__ float fexp2(float x) {
#if __has_builtin(__builtin_amdgcn_exp2f)
    return __builtin_amdgcn_exp2f(x);
#else
    return __expf(x * 0.6931471805599453f);
#endif
}
__device__ __forceinline__ float ffract(float x) {
#if __has_builtin(__builtin_amdgcn_fractf)
    return __builtin_amdgcn_fractf(x);
#else
    return x - floorf(x);
#endif
}

__global__ __launch_bounds__(NT) void psf_sample_kernel(
    const float* __restrict__ vol,         // [256^3]
    const float* __restrict__ sampleGrid,  // [B,3]
    const float* __restrict__ ax,          // [B,6]
    const float* __restrict__ bound,       // [B,2,3]
    const float* __restrict__ invcov,      // [B,3,3] (symmetric)
    const float* __restrict__ xyz,         // [B,n,3]
    float* __restrict__ out,               // [B]
    int n, int B)
{
    const int tid  = threadIdx.x;
    const int wid  = tid >> 6;
    const int lane = tid & 63;
    const int pb   = wid >> 1;      // batch slot within block (0,1)
    const int sw   = wid & 1;       // subwave within batch (0,1)
    const int b    = blockIdx.x * 2 + pb;
    const bool valid = b < B;

    __shared__ float4 s_q[2][RS * QSLICE];   // 2 x 576 x 16B = 18432 B
    __shared__ float  s_red[8];

    const float LOG2E = 1.4426950408889634f;
    float cix = 0, ciy = 0, ciz = 0, hx = 0, hy = 0, hz = 0, addrC = 0;
    float Bxx = 0, Byy = 0, Bzz = 0, Bxy = 0, Bxz = 0, Byz = 0;
    bool fast = false;

    if (valid) {
        // ---- per-batch params (wave-uniform; redundant per lane, SGPR-ified) ----
        const float v0 = ax[b*6+0], v1 = ax[b*6+1], v2 = ax[b*6+2];
        const float t0 = ax[b*6+3], t1 = ax[b*6+4], t2 = ax[b*6+5];
        const float theta = sqrtf(v0*v0 + v1*v1 + v2*v2 + 1e-12f);
        const float inv = 1.0f / theta;
        const float kx = v0*inv, ky = v1*inv, kz = v2*inv;
        const float sn = __sinf(theta);
        const float cn = 1.0f - __cosf(theta);
        const float R00 = 1.0f - cn*(ky*ky + kz*kz);
        const float R01 = -sn*kz + cn*kx*ky;
        const float R02 =  sn*ky + cn*kx*kz;
        const float R10 =  sn*kz + cn*kx*ky;
        const float R11 = 1.0f - cn*(kx*kx + kz*kz);
        const float R12 = -sn*kx + cn*ky*kz;
        const float R20 = -sn*ky + cn*kx*kz;
        const float R21 =  sn*kx + cn*ky*kz;
        const float R22 = 1.0f - cn*(kx*kx + ky*ky);
        const float g0 = sampleGrid[b*3+0] + t0;
        const float g1 = sampleGrid[b*3+1] + t1;
        const float g2 = sampleGrid[b*3+2] + t2;
        const float ms0 = R00*g0 + R01*g1 + R02*g2;
        const float ms1 = R10*g0 + R11*g1 + R12*g2;
        const float ms2 = R20*g0 + R21*g1 + R22*g2;
        const float h0 = (bound[b*6+3] - bound[b*6+0]) * 0.5f;
        const float h1 = (bound[b*6+4] - bound[b*6+1]) * 0.5f;
        const float h2 = (bound[b*6+5] - bound[b*6+2]) * 0.5f;
        const float M00 = invcov[b*9+0], M01 = invcov[b*9+1], M02 = invcov[b*9+2];
        const float M11 = invcov[b*9+4], M12 = invcov[b*9+5], M22 = invcov[b*9+8];

        Bxx = rflf(-0.5f * M00 * h0 * h0 * LOG2E);
        Byy = rflf(-0.5f * M11 * h1 * h1 * LOG2E);
        Bzz = rflf(-0.5f * M22 * h2 * h2 * LOG2E);
        Bxy = rflf(-M01 * h0 * h1 * LOG2E);
        Bxz = rflf(-M02 * h0 * h2 * LOG2E);
        Byz = rflf(-M12 * h1 * h2 * LOG2E);

        const float kk = 256.0f / 255.0f;
        cix = rflf(fmaf(ms0, kk, -0.5f));
        ciy = rflf(fmaf(ms1, kk, -0.5f));
        ciz = rflf(fmaf(ms2, kk, -0.5f));
        hx  = rflf(h0 * kk);
        hy  = rflf(h1 * kk);
        hz  = rflf(h2 * kk);

        const int bx = __builtin_amdgcn_readfirstlane((int)floorf(cix - hx - 1e-3f));
        const int by = __builtin_amdgcn_readfirstlane((int)floorf(ciy - hy - 1e-3f));
        const int bz = __builtin_amdgcn_readfirstlane((int)floorf(ciz - hz - 1e-3f));
        addrC = rflf((float)(bz * QSLICE + by * QROW + bx));
        fast = (hx <= 2.9f) && (hy <= 2.9f) && (hz <= 2.9f);

        if (fast) {
            // stage 4 z-slices per wave; pre-differenced quad per slot:
            // {v00, v10-v00, v01-v00, v11-v10-v01+v00}
            const int lx = lane & 7, ly = lane >> 3;
            #pragma unroll
            for (int p = 0; p < 4; ++p) {
                const int z  = sw * 4 + p;
                const int gx = bx + lx, gy = by + ly, gz = bz + z;
                float v = 0.0f;
                if ((unsigned)gx < (unsigned)DIMV && (unsigned)gy < (unsigned)DIMV &&
                    (unsigned)gz < (unsigned)DIMV)
                    v = vol[((size_t)gz * DIMV + gy) * DIMV + gx];
                const float v10 = __shfl(v, (lane + 1) & 63);
                const float v01 = __shfl(v, (lane + 8) & 63);
                const float v11 = __shfl(v, (lane + 9) & 63);
                const float dx  = v10 - v;
                const float dy  = v01 - v;
                const float dxy = (v11 - v10) - dy;
                // lx==7 / ly==7 slots hold garbage diffs; never read (x0,y0 <= 6)
                s_q[pb][(z * RS + ly) * QROW + lx] = make_float4(v, dx, dy, dxy);
            }
        }
    }
    __syncthreads();

    float sum_wx = 0.0f, sum_w = 0.0f;

    if (valid) {
        const float4* __restrict__ sreg = s_q[pb];

        auto doSample = [&](float rx, float ry, float rz) {
            const float ex = fexp2(rx * -LOG2E);
            const float ey = fexp2(ry * -LOG2E);
            const float ez = fexp2(rz * -LOG2E);
            const float sx = (1.0f - ex) * __builtin_amdgcn_rcpf(1.0f + ex);
            const float sy = (1.0f - ey) * __builtin_amdgcn_rcpf(1.0f + ey);
            const float sz = (1.0f - ez) * __builtin_amdgcn_rcpf(1.0f + ez);

            const float ixf = fmaf(sx, hx, cix);
            const float iyf = fmaf(sy, hy, ciy);
            const float izf = fmaf(sz, hz, ciz);
            const float x0f = floorf(ixf), y0f = floorf(iyf), z0f = floorf(izf);
            const float fx = ffract(ixf), fy = ffract(iyf), fz = ffract(izf);

            float val;
            if (fast) {
                const float ef = fmaf(z0f, (float)QSLICE,
                                 fmaf(y0f, (float)QROW, x0f - addrC));
                const int e = (int)ef;
                const float4 q0 = sreg[e];            // z0: {v, dx, dy, dxy}
                const float4 q1 = sreg[e + QSLICE];   // z1
                const float fxy = fx * fy;
                const float a0 = fmaf(fxy, q0.w, fmaf(fy, q0.z, fmaf(fx, q0.y, q0.x)));
                const float a1 = fmaf(fxy, q1.w, fmaf(fy, q1.z, fmaf(fx, q1.y, q1.x)));
                val = fmaf(fz, a1 - a0, a0);
            } else {
                const int x0 = (int)x0f, y0 = (int)y0f, z0 = (int)z0f;
                const int x1 = x0 + 1, y1 = y0 + 1, z1 = z0 + 1;
                const bool vx0 = (unsigned)x0 < (unsigned)DIMV;
                const bool vx1 = (unsigned)x1 < (unsigned)DIMV;
                const bool vy0 = (unsigned)y0 < (unsigned)DIMV;
                const bool vy1 = (unsigned)y1 < (unsigned)DIMV;
                const bool vz0 = (unsigned)z0 < (unsigned)DIMV;
                const bool vz1 = (unsigned)z1 < (unsigned)DIMV;
                const int cx0 = min(max(x0,0),DIMV-1), cx1 = min(max(x1,0),DIMV-1);
                const int cy0 = min(max(y0,0),DIMV-1), cy1 = min(max(y1,0),DIMV-1);
                const int cz0 = min(max(z0,0),DIMV-1), cz1 = min(max(z1,0),DIMV-1);
                const float wx0 = 1.0f-fx, wx1 = fx, wy0 = 1.0f-fy, wy1 = fy;
                const float wz0 = 1.0f-fz, wz1 = fz;
                const int r00 = (cz0*DIMV + cy0)*DIMV, r01 = (cz0*DIMV + cy1)*DIMV;
                const int r10 = (cz1*DIMV + cy0)*DIMV, r11 = (cz1*DIMV + cy1)*DIMV;
                val  = (vz0&&vy0&&vx0) ? vol[r00+cx0]*(wz0*wy0*wx0) : 0.0f;
                val += (vz0&&vy0&&vx1) ? vol[r00+cx1]*(wz0*wy0*wx1) : 0.0f;
                val += (vz0&&vy1&&vx0) ? vol[r01+cx0]*(wz0*wy1*wx0) : 0.0f;
                val += (vz0&&vy1&&vx1) ? vol[r01+cx1]*(wz0*wy1*wx1) : 0.0f;
                val += (vz1&&vy0&&vx0) ? vol[r10+cx0]*(wz1*wy0*wx0) : 0.0f;
                val += (vz1&&vy0&&vx1) ? vol[r10+cx1]*(wz1*wy0*wx1) : 0.0f;
                val += (vz1&&vy1&&vx0) ? vol[r11+cx0]*(wz1*wy1*wx0) : 0.0f;
                val += (vz1&&vy1&&vx1) ? vol[r11+cx1]*(wz1*wy1*wx1) : 0.0f;
            }

            // nested quadratic
            const float i1 = fmaf(Bxx, sx, fmaf(Bxy, sy, Bxz * sz));
            const float i2 = fmaf(Byy, sy, Byz * sz);
            const float i3 = Bzz * sz;
            const float f  = fmaf(sx, i1, fmaf(sy, i2, sz * i3));
            const float w = fexp2(f);
            sum_w  += w;
            sum_wx = fmaf(w, val, sum_wx);
        };

        // depth-2 software pipeline over 4-sample groups (3 float4 each).
        // sched_barrier(0) pins the prefetch loads ABOVE the current group's
        // compute so the compiler cannot sink them to their use (R9 failure
        // mode: VGPR=40 meant the pipeline was de-scheduled). No launch_bounds
        // minimum: allocator is free to keep ~24 regs of staged data live.
        const int ng = n >> 2;
        const float4* __restrict__ xb4 =
            reinterpret_cast<const float4*>(xyz + (size_t)b * n * 3);
        int g = lane + 64 * sw;
        bool have = g < ng;
        float4 a0, a1, a2;
        if (have) { a0 = xb4[g*3+0]; a1 = xb4[g*3+1]; a2 = xb4[g*3+2]; }
        while (have) {
            const int gn = g + 128;
            const bool haveN = gn < ng;
            float4 c0, c1, c2;
            if (haveN) { c0 = xb4[gn*3+0]; c1 = xb4[gn*3+1]; c2 = xb4[gn*3+2]; }
            __builtin_amdgcn_sched_barrier(0);   // loads may not sink below here
            doSample(a0.x, a0.y, a0.z);
            doSample(a0.w, a1.x, a1.y);
            doSample(a1.z, a1.w, a2.x);
            doSample(a2.y, a2.z, a2.w);
            a0 = c0; a1 = c1; a2 = c2;
            g = gn; have = haveN;
        }
        // generic tail (unused when n % 4 == 0)
        const float* __restrict__ xb = xyz + (size_t)b * n * 3;
        for (int i = (ng << 2) + lane + 64 * sw; i < n; i += 128)
            doSample(xb[i*3+0], xb[i*3+1], xb[i*3+2]);

        // wave64 reduction -> per-wave partials
        #pragma unroll
        for (int off = 32; off > 0; off >>= 1) {
            sum_wx += __shfl_down(sum_wx, off);
            sum_w  += __shfl_down(sum_w,  off);
        }
        if (lane == 0) { s_red[wid*2] = sum_wx; s_red[wid*2+1] = sum_w; }
    }
    __syncthreads();

    // combine the two waves of each batch; one lane writes out[b]
    if (valid && lane == 0 && sw == 0) {
        const float twx = s_red[wid*2] + s_red[(wid+1)*2];
        const float tw  = s_red[wid*2+1] + s_red[(wid+1)*2+1];
        out[b] = twx / tw;
    }
}

extern "C" void kernel_launch(void* const* d_in, const int* in_sizes, int n_in,
                              void* d_out, int out_size, void* d_ws, size_t ws_size,
                              hipStream_t stream) {
    const float* vol        = (const float*)d_in[0];
    const float* sampleGrid = (const float*)d_in[1];
    const float* ax         = (const float*)d_in[2];
    const float* bound      = (const float*)d_in[3];
    const float* invcov     = (const float*)d_in[4];
    // d_in[5] = psf_sigma (unused by reference)
    const float* xyz        = (const float*)d_in[6];
    float* out              = (float*)d_out;

    const int B = in_sizes[1] / 3;
    const int n = in_sizes[6] / (B * 3);

    const int grid = (B + 1) / 2;   // 2 batches per block
    psf_sample_kernel<<<grid, NT, 0, stream>>>(vol, sampleGrid, ax, bound,
                                               invcov, xyz, out, n, B);
}

// Round 11
// 28.364 us; speedup vs baseline: 1.1125x; 1.1125x over previous
//
#include <hip/hip_runtime.h>
#include <hip/hip_fp16.h>
#include <math.h>

constexpr int NT   = 256;   // threads per block (4 waves = 4 batches)
constexpr int WPB  = 4;     // waves per block = batches per block
constexpr int DIMV = 256;   // volume D=H=W
constexpr int RS   = 8;     // staged region side (voxels)
constexpr int QROW = 9;     // packed row stride (slots)
constexpr int QSLICE = RS * QROW;   // 72 slots per z-slice

__device__ __forceinline__ float rflf(float x) {
    return __uint_as_float(__builtin_amdgcn_readfirstlane(__float_as_uint(x)));
}
__device__ __forceinline__ float fexp2(float x) {
#if __has_builtin(__builtin_amdgcn_exp2f)
    return __builtin_amdgcn_exp2f(x);
#else
    return __expf(x * 0.6931471805599453f);
#endif
}
__device__ __forceinline__ float ffract(float x) {
#if __has_builtin(__builtin_amdgcn_fractf)
    return __builtin_amdgcn_fractf(x);
#else
    return x - floorf(x);
#endif
}
__device__ __forceinline__ unsigned pk16(float a, float b) {
    // v_cvt_pkrtz_f16_f32: two f32 -> packed half2 in one instruction
    __half2 h = __float22half2_rn(make_float2(a, b));
    return __builtin_bit_cast(unsigned, h);
}
__device__ __forceinline__ __half2 u2h(unsigned u) {
    return __builtin_bit_cast(__half2, u);
}

__global__ __launch_bounds__(NT, 4) void psf_sample_kernel(
    const float* __restrict__ vol,         // [256^3]
    const float* __restrict__ sampleGrid,  // [B,3]
    const float* __restrict__ ax,          // [B,6]
    const float* __restrict__ bound,       // [B,2,3]
    const float* __restrict__ invcov,      // [B,3,3] (symmetric)
    const float* __restrict__ xyz,         // [B,n,3]
    float* __restrict__ out,               // [B]
    int n, int B)
{
    const int tid  = threadIdx.x;
    const int wid  = tid >> 6;
    const int lane = tid & 63;
    const int b    = blockIdx.x * WPB + wid;
    const bool valid = b < B;

    // slot = {half2(v[z],v[z+1]), half2(dx,dx'), half2(dy,dy'), half2(dxy,dxy')}
    // -> ONE ds_read_b128 per sample covers both z-slices.
    __shared__ uint4 s_q[WPB][RS * QSLICE];   // 4 x 576 x 16B = 36864 B

    const float LOG2E = 1.4426950408889634f;
    float cix = 0, ciy = 0, ciz = 0, hx = 0, hy = 0, hz = 0, addrC = 0;
    float Bxx = 0, Byy = 0, Bzz = 0, Bxy = 0, Bxz = 0, Byz = 0;
    bool fast = false;

    if (valid) {
        // ---- per-batch params (wave-uniform; redundant per lane, SGPR-ified) ----
        const float v0 = ax[b*6+0], v1 = ax[b*6+1], v2 = ax[b*6+2];
        const float t0 = ax[b*6+3], t1 = ax[b*6+4], t2 = ax[b*6+5];
        const float theta = sqrtf(v0*v0 + v1*v1 + v2*v2 + 1e-12f);
        const float inv = 1.0f / theta;
        const float kx = v0*inv, ky = v1*inv, kz = v2*inv;
        const float sn = __sinf(theta);
        const float cn = 1.0f - __cosf(theta);
        const float R00 = 1.0f - cn*(ky*ky + kz*kz);
        const float R01 = -sn*kz + cn*kx*ky;
        const float R02 =  sn*ky + cn*kx*kz;
        const float R10 =  sn*kz + cn*kx*ky;
        const float R11 = 1.0f - cn*(kx*kx + kz*kz);
        const float R12 = -sn*kx + cn*ky*kz;
        const float R20 = -sn*ky + cn*kx*kz;
        const float R21 =  sn*kx + cn*ky*kz;
        const float R22 = 1.0f - cn*(kx*kx + ky*ky);
        const float g0 = sampleGrid[b*3+0] + t0;
        const float g1 = sampleGrid[b*3+1] + t1;
        const float g2 = sampleGrid[b*3+2] + t2;
        const float ms0 = R00*g0 + R01*g1 + R02*g2;
        const float ms1 = R10*g0 + R11*g1 + R12*g2;
        const float ms2 = R20*g0 + R21*g1 + R22*g2;
        const float h0 = (bound[b*6+3] - bound[b*6+0]) * 0.5f;
        const float h1 = (bound[b*6+4] - bound[b*6+1]) * 0.5f;
        const float h2 = (bound[b*6+5] - bound[b*6+2]) * 0.5f;
        const float M00 = invcov[b*9+0], M01 = invcov[b*9+1], M02 = invcov[b*9+2];
        const float M11 = invcov[b*9+4], M12 = invcov[b*9+5], M22 = invcov[b*9+8];

        Bxx = rflf(-0.5f * M00 * h0 * h0 * LOG2E);
        Byy = rflf(-0.5f * M11 * h1 * h1 * LOG2E);
        Bzz = rflf(-0.5f * M22 * h2 * h2 * LOG2E);
        Bxy = rflf(-M01 * h0 * h1 * LOG2E);
        Bxz = rflf(-M02 * h0 * h2 * LOG2E);
        Byz = rflf(-M12 * h1 * h2 * LOG2E);

        const float kk = 256.0f / 255.0f;
        cix = rflf(fmaf(ms0, kk, -0.5f));
        ciy = rflf(fmaf(ms1, kk, -0.5f));
        ciz = rflf(fmaf(ms2, kk, -0.5f));
        hx  = rflf(h0 * kk);
        hy  = rflf(h1 * kk);
        hz  = rflf(h2 * kk);

        const int bx = __builtin_amdgcn_readfirstlane((int)floorf(cix - hx - 1e-3f));
        const int by = __builtin_amdgcn_readfirstlane((int)floorf(ciy - hy - 1e-3f));
        const int bz = __builtin_amdgcn_readfirstlane((int)floorf(ciz - hz - 1e-3f));
        addrC = rflf((float)(bz * QSLICE + by * QROW + bx));
        fast = (hx <= 2.9f) && (hy <= 2.9f) && (hz <= 2.9f);

        if (fast) {
            // wave stages its batch's 8^3 region, one z-slice per pass,
            // quad-diffs via shuffles, z-pair packed to fp16 on the fly.
            const int lx = lane & 7, ly = lane >> 3;
            float pv = 0.0f, pdx = 0.0f, pdy = 0.0f, pdxy = 0.0f;
            #pragma unroll
            for (int p = 0; p < RS; ++p) {
                const int gx = bx + lx, gy = by + ly, gz = bz + p;
                float v = 0.0f;
                if ((unsigned)gx < (unsigned)DIMV && (unsigned)gy < (unsigned)DIMV &&
                    (unsigned)gz < (unsigned)DIMV)
                    v = vol[((size_t)gz * DIMV + gy) * DIMV + gx];
                const float v10 = __shfl(v, (lane + 1) & 63);
                const float v01 = __shfl(v, (lane + 8) & 63);
                const float v11 = __shfl(v, (lane + 9) & 63);
                const float dx  = v10 - v;
                const float dy  = v01 - v;
                const float dxy = (v11 - v10) - dy;
                if (p > 0) {
                    // slot z=p-1 pairs slice p-1 (lo) with slice p (hi).
                    // lx==7 / ly==7 slots hold garbage diffs; never read.
                    s_q[wid][((p - 1) * RS + ly) * QROW + lx] =
                        make_uint4(pk16(pv, v), pk16(pdx, dx),
                                   pk16(pdy, dy), pk16(pdxy, dxy));
                }
                pv = v; pdx = dx; pdy = dy; pdxy = dxy;
            }
        }
    }
    __syncthreads();

    if (valid) {
        float sum_wx = 0.0f, sum_w = 0.0f;
        const uint4* __restrict__ sreg = s_q[wid];

        auto doSample = [&](float rx, float ry, float rz) {
            const float ex = fexp2(rx * -LOG2E);
            const float ey = fexp2(ry * -LOG2E);
            const float ez = fexp2(rz * -LOG2E);
            const float sx = (1.0f - ex) * __builtin_amdgcn_rcpf(1.0f + ex);
            const float sy = (1.0f - ey) * __builtin_amdgcn_rcpf(1.0f + ey);
            const float sz = (1.0f - ez) * __builtin_amdgcn_rcpf(1.0f + ez);

            const float ixf = fmaf(sx, hx, cix);
            const float iyf = fmaf(sy, hy, ciy);
            const float izf = fmaf(sz, hz, ciz);
            const float x0f = floorf(ixf), y0f = floorf(iyf), z0f = floorf(izf);
            const float fx = ffract(ixf), fy = ffract(iyf), fz = ffract(izf);

            float val;
            if (fast) {
                const float ef = fmaf(z0f, (float)QSLICE,
                                 fmaf(y0f, (float)QROW, x0f - addrC));
                const int e = (int)ef;
                const uint4 q = sreg[e];               // single b128: both z-slices
                const __half2 v01  = u2h(q.x);
                const __half2 dx01 = u2h(q.y);
                const __half2 dy01 = u2h(q.z);
                const __half2 dxy01= u2h(q.w);
                const __half2 fx2  = __float2half2_rn(fx);
                const __half2 fy2  = __float2half2_rn(fy);
                const __half2 fxy2 = __hmul2(fx2, fy2);
                const __half2 acc  = __hfma2(fxy2, dxy01,
                                     __hfma2(fy2, dy01,
                                     __hfma2(fx2, dx01, v01)));
                const float a0 = __low2float(acc);     // bilinear at z0
                const float a1 = __high2float(acc);    // bilinear at z0+1
                val = fmaf(fz, a1 - a0, a0);
            } else {
                const int x0 = (int)x0f, y0 = (int)y0f, z0 = (int)z0f;
                const int x1 = x0 + 1, y1 = y0 + 1, z1 = z0 + 1;
                const bool vx0 = (unsigned)x0 < (unsigned)DIMV;
                const bool vx1 = (unsigned)x1 < (unsigned)DIMV;
                const bool vy0 = (unsigned)y0 < (unsigned)DIMV;
                const bool vy1 = (unsigned)y1 < (unsigned)DIMV;
                const bool vz0 = (unsigned)z0 < (unsigned)DIMV;
                const bool vz1 = (unsigned)z1 < (unsigned)DIMV;
                const int cx0 = min(max(x0,0),DIMV-1), cx1 = min(max(x1,0),DIMV-1);
                const int cy0 = min(max(y0,0),DIMV-1), cy1 = min(max(y1,0),DIMV-1);
                const int cz0 = min(max(z0,0),DIMV-1), cz1 = min(max(z1,0),DIMV-1);
                const float wx0 = 1.0f-fx, wx1 = fx, wy0 = 1.0f-fy, wy1 = fy;
                const float wz0 = 1.0f-fz, wz1 = fz;
                const int r00 = (cz0*DIMV + cy0)*DIMV, r01 = (cz0*DIMV + cy1)*DIMV;
                const int r10 = (cz1*DIMV + cy0)*DIMV, r11 = (cz1*DIMV + cy1)*DIMV;
                val  = (vz0&&vy0&&vx0) ? vol[r00+cx0]*(wz0*wy0*wx0) : 0.0f;
                val += (vz0&&vy0&&vx1) ? vol[r00+cx1]*(wz0*wy0*wx1) : 0.0f;
                val += (vz0&&vy1&&vx0) ? vol[r01+cx0]*(wz0*wy1*wx0) : 0.0f;
                val += (vz0&&vy1&&vx1) ? vol[r01+cx1]*(wz0*wy1*wx1) : 0.0f;
                val += (vz1&&vy0&&vx0) ? vol[r10+cx0]*(wz1*wy0*wx0) : 0.0f;
                val += (vz1&&vy0&&vx1) ? vol[r10+cx1]*(wz1*wy0*wx1) : 0.0f;
                val += (vz1&&vy1&&vx0) ? vol[r11+cx0]*(wz1*wy1*wx0) : 0.0f;
                val += (vz1&&vy1&&vx1) ? vol[r11+cx1]*(wz1*wy1*wx1) : 0.0f;
            }

            const float i1 = fmaf(Bxx, sx, fmaf(Bxy, sy, Bxz * sz));
            const float i2 = fmaf(Byy, sy, Byz * sz);
            const float i3 = Bzz * sz;
            const float f  = fmaf(sx, i1, fmaf(sy, i2, sz * i3));
            const float w = fexp2(f);
            sum_w  += w;
            sum_wx = fmaf(w, val, sum_wx);
        };

        // 32 samples/lane: 8 groups of 4 via 3 coalesced float4 loads each
        const int ng = n >> 2;
        const float4* __restrict__ xb4 =
            reinterpret_cast<const float4*>(xyz + (size_t)b * n * 3);
        for (int g = lane; g < ng; g += 64) {
            const float4 q0 = xb4[g*3 + 0];
            const float4 q1 = xb4[g*3 + 1];
            const float4 q2 = xb4[g*3 + 2];
            doSample(q0.x, q0.y, q0.z);
            doSample(q0.w, q1.x, q1.y);
            doSample(q1.z, q1.w, q2.x);
            doSample(q2.y, q2.z, q2.w);
        }
        // generic tail (unused when n % 4 == 0)
        const float* __restrict__ xb = xyz + (size_t)b * n * 3;
        for (int i = (ng << 2) + lane; i < n; i += 64)
            doSample(xb[i*3+0], xb[i*3+1], xb[i*3+2]);

        // wave64 reduction; lane 0 writes the batch's output
        #pragma unroll
        for (int off = 32; off > 0; off >>= 1) {
            sum_wx += __shfl_down(sum_wx, off);
            sum_w  += __shfl_down(sum_w,  off);
        }
        if (lane == 0) out[b] = sum_wx / sum_w;
    }
}

extern "C" void kernel_launch(void* const* d_in, const int* in_sizes, int n_in,
                              void* d_out, int out_size, void* d_ws, size_t ws_size,
                              hipStream_t stream) {
    const float* vol        = (const float*)d_in[0];
    const float* sampleGrid = (const float*)d_in[1];
    const float* ax         = (const float*)d_in[2];
    const float* bound      = (const float*)d_in[3];
    const float* invcov     = (const float*)d_in[4];
    // d_in[5] = psf_sigma (unused by reference)
    const float* xyz        = (const float*)d_in[6];
    float* out              = (float*)d_out;

    const int B = in_sizes[1] / 3;
    const int n = in_sizes[6] / (B * 3);

    const int grid = (B + WPB - 1) / WPB;
    psf_sample_kernel<<<grid, NT, 0, stream>>>(vol, sampleGrid, ax, bound,
                                               invcov, xyz, out, n, B);
}